// Round 15
// baseline (339.353 us; speedup 1.0000x reference)
//
#include <hip/hip_runtime.h>

// Problem dims (fixed by reference): N=50000, E=800000, D_IN=128, D_H=64, B=64
constexpr int DI = 128;
constexpr int DH = 64;
constexpr int NB = 64;
constexpr int PS = 8;    // pool split factor
constexpr int SLOTS = 64; // fixed adj slots per node (Poisson(16): P(deg>64) ~ 1e-12)
constexpr int NXCD = 8;  // XCDs on MI355X; blockIdx%8 round-robins (perf heuristic only)
constexpr int NPASS = 8; // gather src-tile passes (tile = 1.6MB of g, fits XCD L2)

// LESSONS ENCODED HERE:
//  - r9: NO __threadfence last-block-done fusions (L2 writeback storm, +66us).
//  - r10: parallel-path thresholds must cover the Poisson(16) tail.
//  - r12: adj bucket ORDER need not be deterministic (fp reorder << threshold).
//  - r13: fixed-slot adj kills the count/scan chain; cursor doubles as degree.
//  - r14: fill int4-vectorization neutral -> fill is at its atomic floor.

__global__ void k_zero(int4* __restrict__ p, int nw4) {
    int i = blockIdx.x * 256 + threadIdx.x;
    if (i < nw4) p[i] = make_int4(0, 0, 0, 0);
}

// Single-pass count+fill, XCD-partitioned + int4-vectorized. After this
// kernel cursor[d] == in-degree(d).
__global__ void k_fill(const int4* __restrict__ src4, const int4* __restrict__ dst4,
                       int* __restrict__ cursor, int* __restrict__ adj,
                       int e4, int chunk) {
    int part = blockIdx.x & (NXCD - 1);
    int i = (blockIdx.x >> 3) * 256 + threadIdx.x;
    if (i >= e4) return;
    int4 d = dst4[i];
    int plo = part * chunk, phi = plo + chunk;
    bool inx = (d.x >= plo) & (d.x < phi);
    bool iny = (d.y >= plo) & (d.y < phi);
    bool inz = (d.z >= plo) & (d.z < phi);
    bool inw = (d.w >= plo) & (d.w < phi);
    if (!(inx | iny | inz | inw)) return;
    int4 s = src4[i];
    if (inx) { int p = atomicAdd(&cursor[d.x], 1); if (p < SLOTS) adj[d.x * SLOTS + p] = s.x; }
    if (iny) { int p = atomicAdd(&cursor[d.y], 1); if (p < SLOTS) adj[d.y * SLOTS + p] = s.y; }
    if (inz) { int p = atomicAdd(&cursor[d.z], 1); if (p < SLOTS) adj[d.z * SLOTS + p] = s.z; }
    if (inw) { int p = atomicAdd(&cursor[d.w], 1); if (p < SLOTS) adj[d.w * SLOTS + p] = s.w; }
}

// ---------- layers ----------
__device__ __forceinline__ void fma4(float4& acc, float s, const float4& w) {
    acc.x = fmaf(s, w.x, acc.x);
    acc.y = fmaf(s, w.y, acc.y);
    acc.z = fmaf(s, w.z, acc.z);
    acc.w = fmaf(s, w.w, acc.w);
}

__device__ __forceinline__ float dinv_of(int c) {
    return 1.0f / sqrtf(1.0f + (float)c);  // same expression as the validated scan3
}

// g = (act(in) @ W) * dinv, LDS-tiled register-blocked GEMM.
// Block: 64 nodes x 64 feats, 256 threads as 16x16, 4x4 outputs/thread.
template <int K, bool RELU>
__global__ __launch_bounds__(256) void k_matmul(const float4* __restrict__ in4,
                                                const float4* __restrict__ W4,
                                                const float4* __restrict__ b4,
                                                const int* __restrict__ cnt,
                                                float4* __restrict__ g4, int n) {
    __shared__ float4 Wl[K * 16];    // [K][64] floats
    __shared__ float4 Al[64 * 17];   // [64][68] floats (pad 4)
    const int t = threadIdx.x;
    for (int i = t; i < K * 16; i += 256) Wl[i] = W4[i];

    const int tx = t & 15;          // feature group: 4*tx .. 4*tx+3
    const int ty = t >> 4;          // node group:    4*ty .. 4*ty+3
    const int node0 = blockIdx.x * 64;
    constexpr int K4 = K / 4;

    float4 acc0 = {0,0,0,0}, acc1 = {0,0,0,0}, acc2 = {0,0,0,0}, acc3 = {0,0,0,0};

#pragma unroll
    for (int ph = 0; ph < K / 64; ++ph) {
        __syncthreads();  // also covers initial W staging
#pragma unroll
        for (int s = 0; s < 4; ++s) {
            int i = t + s * 256;          // 64 rows x 16 float4
            int r = i >> 4, k4 = i & 15;
            int node = node0 + r;
            if (node >= n) node = n - 1;  // clamp (dup rows harmless)
            float4 v = in4[(size_t)node * K4 + ph * 16 + k4];
            if (RELU) {
                float4 bb = b4[ph * 16 + k4];
                v.x = fmaxf(v.x + bb.x, 0.f);
                v.y = fmaxf(v.y + bb.y, 0.f);
                v.z = fmaxf(v.z + bb.z, 0.f);
                v.w = fmaxf(v.w + bb.w, 0.f);
            }
            Al[r * 17 + k4] = v;
        }
        __syncthreads();
#pragma unroll 4
        for (int k4 = 0; k4 < 16; ++k4) {
            float4 a0 = Al[(4 * ty + 0) * 17 + k4];
            float4 a1 = Al[(4 * ty + 1) * 17 + k4];
            float4 a2 = Al[(4 * ty + 2) * 17 + k4];
            float4 a3 = Al[(4 * ty + 3) * 17 + k4];
            const float4* wrow = &Wl[(ph * 64 + 4 * k4) * 16 + tx];
            float4 w0 = wrow[0];
            float4 w1 = wrow[16];
            float4 w2 = wrow[32];
            float4 w3 = wrow[48];
            fma4(acc0, a0.x, w0); fma4(acc0, a0.y, w1); fma4(acc0, a0.z, w2); fma4(acc0, a0.w, w3);
            fma4(acc1, a1.x, w0); fma4(acc1, a1.y, w1); fma4(acc1, a1.z, w2); fma4(acc1, a1.w, w3);
            fma4(acc2, a2.x, w0); fma4(acc2, a2.y, w1); fma4(acc2, a2.z, w2); fma4(acc2, a2.w, w3);
            fma4(acc3, a3.x, w0); fma4(acc3, a3.y, w1); fma4(acc3, a3.z, w2); fma4(acc3, a3.w, w3);
        }
    }

    int nb = node0 + 4 * ty;
    if (nb + 0 < n) { float dv = dinv_of(cnt[nb + 0]);
        float4 r; r.x = acc0.x * dv; r.y = acc0.y * dv; r.z = acc0.z * dv; r.w = acc0.w * dv;
        g4[(size_t)(nb + 0) * 16 + tx] = r; }
    if (nb + 1 < n) { float dv = dinv_of(cnt[nb + 1]);
        float4 r; r.x = acc1.x * dv; r.y = acc1.y * dv; r.z = acc1.z * dv; r.w = acc1.w * dv;
        g4[(size_t)(nb + 1) * 16 + tx] = r; }
    if (nb + 2 < n) { float dv = dinv_of(cnt[nb + 2]);
        float4 r; r.x = acc2.x * dv; r.y = acc2.y * dv; r.z = acc2.z * dv; r.w = acc2.w * dv;
        g4[(size_t)(nb + 2) * 16 + tx] = r; }
    if (nb + 3 < n) { float dv = dinv_of(cnt[nb + 3]);
        float4 r; r.x = acc3.x * dv; r.y = acc3.y * dv; r.z = acc3.z * dv; r.w = acc3.w * dv;
        g4[(size_t)(nb + 3) * 16 + tx] = r; }
}

// agg[d] = dv_d * ( g[d] + sum_{s in N(d)} g[s] )
// r15: src-tile passes. adj bucket lives in registers (av); sweep NPASS tiles
// of the src range; in pass p a group loads a row only if that slot's src is
// in tile p (predicate group-uniform: same slot -> same src). All resident
// waves sweep tiles in the same order -> each XCD's L2 converges to the
// current 1.6MB tile -> g reads become L2 hits instead of 69% L3 misses.
// Each slot still loaded exactly once; summation reorder within r12 envelope.
__global__ __launch_bounds__(256) void k_gather(const int* __restrict__ cnt,
                                                const int* __restrict__ adj,
                                                const float4* __restrict__ g4,
                                                float4* __restrict__ agg4,
                                                int n, int tch) {
    int node = blockIdx.x * 4 + (threadIdx.x >> 6);
    if (node >= n) return;
    int lane = threadIdx.x & 63;
    int grp = lane >> 4, sub = lane & 15;
    int deg = cnt[node];
    if (deg > SLOTS) deg = SLOTS;

    float4 self = g4[(size_t)node * 16 + sub];  // hoisted: overlaps loop latency
    float dvv = dinv_of(deg);

    int av = (lane < deg) ? adj[node * SLOTS + lane] : 0;  // one coalesced load

    float ax = 0.f, ay = 0.f, az = 0.f, aw = 0.f;
    for (int p = 0; p < NPASS; ++p) {
        int tlo = p * tch, thi = tlo + tch;
#pragma unroll 4
        for (int q = 0; q < 16; ++q) {
            if (4 * q >= deg) break;        // wave-uniform exit
            int slot = 4 * q + grp;
            int s = __shfl(av, slot);
            if (slot < deg && s >= tlo && s < thi) {  // uniform per 16-lane group
                float4 v = g4[(size_t)s * 16 + sub];
                ax += v.x; ay += v.y; az += v.z; aw += v.w;
            }
        }
    }
#pragma unroll
    for (int m = 16; m <= 32; m <<= 1) {
        ax += __shfl_xor(ax, m);
        ay += __shfl_xor(ay, m);
        az += __shfl_xor(az, m);
        aw += __shfl_xor(aw, m);
    }
    if (lane < 16) {
        float4 r;
        r.x = (ax + self.x) * dvv;
        r.y = (ay + self.y) * dvv;
        r.z = (az + self.z) * dvv;
        r.w = (aw + self.w) * dvv;
        agg4[(size_t)node * 16 + sub] = r;
    }
}

// ---------- pool + fc ----------
__device__ __forceinline__ int lower_bound_batch(const int* __restrict__ batch, int n, int val) {
    int lo = 0, hi = n;
    while (lo < hi) {
        int mid = (lo + hi) >> 1;
        if (batch[mid] < val) lo = mid + 1; else hi = mid;
    }
    return lo;
}

__global__ void k_pool_part(const float* __restrict__ agg, const float* __restrict__ b3,
                            const int* __restrict__ batch, float* __restrict__ part, int n) {
    int b = blockIdx.x / PS;
    int s = blockIdx.x % PS;
    int lo = lower_bound_batch(batch, n, b);
    int hi = lower_bound_batch(batch, n, b + 1);
    int len = hi - lo;
    int c0 = lo + (int)((long long)len * s / PS);
    int c1 = lo + (int)((long long)len * (s + 1) / PS);

    int j = threadIdx.x & 63;
    int w = threadIdx.x >> 6;
    float bj = b3[j];
    float acc = 0.0f;
    for (int node = c0 + w; node < c1; node += 4)
        acc += fmaxf(agg[(size_t)node * DH + j] + bj, 0.0f);

    __shared__ float red[4][DH];
    red[w][j] = acc;
    __syncthreads();
    if (w == 0)
        part[(b * PS + s) * DH + j] = red[0][j] + red[1][j] + red[2][j] + red[3][j];
}

__global__ void k_fc(const float* __restrict__ part, const int* __restrict__ batch,
                     const float* __restrict__ Wfc, const float* __restrict__ bfc,
                     float* __restrict__ out, int n) {
    int b = blockIdx.x;
    int j = threadIdx.x;  // 64 threads = 1 wave
    int lo = lower_bound_batch(batch, n, b);
    int hi = lower_bound_batch(batch, n, b + 1);
    float c = fmaxf((float)(hi - lo), 1.0f);
    float p = 0.0f;
#pragma unroll
    for (int s = 0; s < PS; ++s) p += part[(b * PS + s) * DH + j];
    p = (p / c) * Wfc[j];
#pragma unroll
    for (int off = 32; off; off >>= 1) p += __shfl_down(p, off);
    if (j == 0) out[b] = p + bfc[0];
}

extern "C" void kernel_launch(void* const* d_in, const int* in_sizes, int n_in,
                              void* d_out, int out_size, void* d_ws, size_t ws_size,
                              hipStream_t stream) {
    const float* x    = (const float*)d_in[0];
    const int* ei     = (const int*)d_in[1];
    const int* batch  = (const int*)d_in[2];
    const float* W1   = (const float*)d_in[3];
    const float* b1   = (const float*)d_in[4];
    const float* W2   = (const float*)d_in[5];
    const float* b2   = (const float*)d_in[6];
    const float* W3   = (const float*)d_in[7];
    const float* b3   = (const float*)d_in[8];
    const float* Wfc  = (const float*)d_in[9];
    const float* bfc  = (const float*)d_in[10];
    float* out = (float*)d_out;

    const int n = in_sizes[0] / DI;  // 50000
    const int e = in_sizes[1] / 2;   // 800000 (divisible by 4; dst = ei+e stays 16B-aligned)
    const int* src = ei;
    const int* dst = ei + e;

    // workspace layout (ws_size = 256 MiB; all blocks 16B-aligned)
    float* h      = (float*)d_ws;               // n*DH
    float* agg    = h + (size_t)n * DH;         // n*DH
    float* part   = agg + (size_t)n * DH;       // NB*PS*DH
    int*   cursor = (int*)(part + NB * PS * DH);// n   (doubles as in-degree after fill)
    int*   adj    = cursor + n;                 // n*SLOTS

    const int e4    = e / 4;          // 200000 int4 edge groups
    const int fb    = (e4 + 255) / 256;
    const int wb4   = (n + 3) / 4;    // 1 wave per node kernels
    const int gmb   = (n + 63) / 64;  // gemm blocks (64 nodes each)
    const int chunk = (n + NXCD - 1) / NXCD;   // dst-partition size (6250)
    const int tch   = (n + NPASS - 1) / NPASS; // gather src-tile size (6250)
    const int zw4   = n / 4;          // cursor int4 words (50000 % 4 == 0)

    // ---- adjacency build: one zero + one fused count/fill pass ----
    k_zero<<<(zw4 + 255) / 256, 256, 0, stream>>>((int4*)cursor, zw4);
    k_fill<<<fb * NXCD, 256, 0, stream>>>((const int4*)src, (const int4*)dst,
                                          cursor, adj, e4, chunk);

    // ---- layers ----
    k_matmul<DI, false><<<gmb, 256, 0, stream>>>((const float4*)x, (const float4*)W1,
                                                 nullptr, cursor, (float4*)h, n);
    k_gather<<<wb4, 256, 0, stream>>>(cursor, adj, (const float4*)h, (float4*)agg, n, tch);
    k_matmul<DH, true><<<gmb, 256, 0, stream>>>((const float4*)agg, (const float4*)W2,
                                                (const float4*)b1, cursor, (float4*)h, n);
    k_gather<<<wb4, 256, 0, stream>>>(cursor, adj, (const float4*)h, (float4*)agg, n, tch);
    k_matmul<DH, true><<<gmb, 256, 0, stream>>>((const float4*)agg, (const float4*)W3,
                                                (const float4*)b2, cursor, (float4*)h, n);
    k_gather<<<wb4, 256, 0, stream>>>(cursor, adj, (const float4*)h, (float4*)agg, n, tch);

    // ---- pool + fc ----
    k_pool_part<<<NB * PS, 256, 0, stream>>>(agg, b3, batch, part, n);
    k_fc<<<NB, DH, 0, stream>>>(part, batch, Wfc, bfc, out, n);
}

// Round 16
// 212.308 us; speedup vs baseline: 1.5984x; 1.5984x over previous
//
#include <hip/hip_runtime.h>

// Problem dims (fixed by reference): N=50000, E=800000, D_IN=128, D_H=64, B=64
constexpr int DI = 128;
constexpr int DH = 64;
constexpr int NB = 64;
constexpr int PS = 8;    // pool split factor
constexpr int SLOTS = 64; // fixed adj slots per node (Poisson(16): P(deg>64) ~ 1e-12)
constexpr int NXCD = 8;  // XCDs on MI355X; blockIdx%8 round-robins (perf heuristic only)

// LESSONS ENCODED HERE:
//  - r9: NO __threadfence last-block-done fusions (L2 writeback storm, +66us).
//  - r10: parallel-path thresholds must cover the Poisson(16) tail.
//  - r12: adj bucket ORDER need not be deterministic (fp reorder << threshold).
//  - r13: fixed-slot adj kills the count/scan chain; cursor doubles as degree.
//  - r14: fill int4-vectorization neutral -> fill is at its atomic floor.
//  - r15: gather src-tile passes REGRESSED 2x: no wave-phase sync -> no L2
//    convergence (FETCH stayed 83MB), and per-pass predicates cut rows-in-
//    flight 16->2 (MLP collapse) while 8x-ing slot-scan VALU. Gather is at
//    the scattered-256B latency/MLP floor; locality needs sync we don't have.

__global__ void k_zero(int4* __restrict__ p, int nw4) {
    int i = blockIdx.x * 256 + threadIdx.x;
    if (i < nw4) p[i] = make_int4(0, 0, 0, 0);
}

// Single-pass count+fill, XCD-partitioned + int4-vectorized. After this
// kernel cursor[d] == in-degree(d).
__global__ void k_fill(const int4* __restrict__ src4, const int4* __restrict__ dst4,
                       int* __restrict__ cursor, int* __restrict__ adj,
                       int e4, int chunk) {
    int part = blockIdx.x & (NXCD - 1);
    int i = (blockIdx.x >> 3) * 256 + threadIdx.x;
    if (i >= e4) return;
    int4 d = dst4[i];
    int plo = part * chunk, phi = plo + chunk;
    bool inx = (d.x >= plo) & (d.x < phi);
    bool iny = (d.y >= plo) & (d.y < phi);
    bool inz = (d.z >= plo) & (d.z < phi);
    bool inw = (d.w >= plo) & (d.w < phi);
    if (!(inx | iny | inz | inw)) return;
    int4 s = src4[i];
    if (inx) { int p = atomicAdd(&cursor[d.x], 1); if (p < SLOTS) adj[d.x * SLOTS + p] = s.x; }
    if (iny) { int p = atomicAdd(&cursor[d.y], 1); if (p < SLOTS) adj[d.y * SLOTS + p] = s.y; }
    if (inz) { int p = atomicAdd(&cursor[d.z], 1); if (p < SLOTS) adj[d.z * SLOTS + p] = s.z; }
    if (inw) { int p = atomicAdd(&cursor[d.w], 1); if (p < SLOTS) adj[d.w * SLOTS + p] = s.w; }
}

// ---------- layers ----------
__device__ __forceinline__ void fma4(float4& acc, float s, const float4& w) {
    acc.x = fmaf(s, w.x, acc.x);
    acc.y = fmaf(s, w.y, acc.y);
    acc.z = fmaf(s, w.z, acc.z);
    acc.w = fmaf(s, w.w, acc.w);
}

__device__ __forceinline__ float dinv_of(int c) {
    return 1.0f / sqrtf(1.0f + (float)c);  // same expression as the validated scan3
}

// g = (act(in) @ W) * dinv, LDS-tiled register-blocked GEMM.
// Block: 64 nodes x 64 feats, 256 threads as 16x16, 4x4 outputs/thread.
template <int K, bool RELU>
__global__ __launch_bounds__(256) void k_matmul(const float4* __restrict__ in4,
                                                const float4* __restrict__ W4,
                                                const float4* __restrict__ b4,
                                                const int* __restrict__ cnt,
                                                float4* __restrict__ g4, int n) {
    __shared__ float4 Wl[K * 16];    // [K][64] floats
    __shared__ float4 Al[64 * 17];   // [64][68] floats (pad 4)
    const int t = threadIdx.x;
    for (int i = t; i < K * 16; i += 256) Wl[i] = W4[i];

    const int tx = t & 15;          // feature group: 4*tx .. 4*tx+3
    const int ty = t >> 4;          // node group:    4*ty .. 4*ty+3
    const int node0 = blockIdx.x * 64;
    constexpr int K4 = K / 4;

    float4 acc0 = {0,0,0,0}, acc1 = {0,0,0,0}, acc2 = {0,0,0,0}, acc3 = {0,0,0,0};

#pragma unroll
    for (int ph = 0; ph < K / 64; ++ph) {
        __syncthreads();  // also covers initial W staging
#pragma unroll
        for (int s = 0; s < 4; ++s) {
            int i = t + s * 256;          // 64 rows x 16 float4
            int r = i >> 4, k4 = i & 15;
            int node = node0 + r;
            if (node >= n) node = n - 1;  // clamp (dup rows harmless)
            float4 v = in4[(size_t)node * K4 + ph * 16 + k4];
            if (RELU) {
                float4 bb = b4[ph * 16 + k4];
                v.x = fmaxf(v.x + bb.x, 0.f);
                v.y = fmaxf(v.y + bb.y, 0.f);
                v.z = fmaxf(v.z + bb.z, 0.f);
                v.w = fmaxf(v.w + bb.w, 0.f);
            }
            Al[r * 17 + k4] = v;
        }
        __syncthreads();
#pragma unroll 4
        for (int k4 = 0; k4 < 16; ++k4) {
            float4 a0 = Al[(4 * ty + 0) * 17 + k4];
            float4 a1 = Al[(4 * ty + 1) * 17 + k4];
            float4 a2 = Al[(4 * ty + 2) * 17 + k4];
            float4 a3 = Al[(4 * ty + 3) * 17 + k4];
            const float4* wrow = &Wl[(ph * 64 + 4 * k4) * 16 + tx];
            float4 w0 = wrow[0];
            float4 w1 = wrow[16];
            float4 w2 = wrow[32];
            float4 w3 = wrow[48];
            fma4(acc0, a0.x, w0); fma4(acc0, a0.y, w1); fma4(acc0, a0.z, w2); fma4(acc0, a0.w, w3);
            fma4(acc1, a1.x, w0); fma4(acc1, a1.y, w1); fma4(acc1, a1.z, w2); fma4(acc1, a1.w, w3);
            fma4(acc2, a2.x, w0); fma4(acc2, a2.y, w1); fma4(acc2, a2.z, w2); fma4(acc2, a2.w, w3);
            fma4(acc3, a3.x, w0); fma4(acc3, a3.y, w1); fma4(acc3, a3.z, w2); fma4(acc3, a3.w, w3);
        }
    }

    int nb = node0 + 4 * ty;
    if (nb + 0 < n) { float dv = dinv_of(cnt[nb + 0]);
        float4 r; r.x = acc0.x * dv; r.y = acc0.y * dv; r.z = acc0.z * dv; r.w = acc0.w * dv;
        g4[(size_t)(nb + 0) * 16 + tx] = r; }
    if (nb + 1 < n) { float dv = dinv_of(cnt[nb + 1]);
        float4 r; r.x = acc1.x * dv; r.y = acc1.y * dv; r.z = acc1.z * dv; r.w = acc1.w * dv;
        g4[(size_t)(nb + 1) * 16 + tx] = r; }
    if (nb + 2 < n) { float dv = dinv_of(cnt[nb + 2]);
        float4 r; r.x = acc2.x * dv; r.y = acc2.y * dv; r.z = acc2.z * dv; r.w = acc2.w * dv;
        g4[(size_t)(nb + 2) * 16 + tx] = r; }
    if (nb + 3 < n) { float dv = dinv_of(cnt[nb + 3]);
        float4 r; r.x = acc3.x * dv; r.y = acc3.y * dv; r.z = acc3.z * dv; r.w = acc3.w * dv;
        g4[(size_t)(nb + 3) * 16 + tx] = r; }
}

// agg[d] = dv_d * ( g[d] + sum_{s in N(d)} g[s] )   [r14 version, reverted]
// Fixed-slot adj: bucket base = node*SLOTS, deg = cnt[node] (<= 64 always).
// Coalesced adj: all 64 lanes load adj[base+lane] in ONE instruction; slot
// srcs distributed via __shfl. 16 lanes per row, 4 lane-groups, up to 16
// rows in flight (the MLP that r15 destroyed).
__global__ __launch_bounds__(256) void k_gather(const int* __restrict__ cnt,
                                                const int* __restrict__ adj,
                                                const float4* __restrict__ g4,
                                                float4* __restrict__ agg4, int n) {
    int node = blockIdx.x * 4 + (threadIdx.x >> 6);
    if (node >= n) return;
    int lane = threadIdx.x & 63;
    int grp = lane >> 4, sub = lane & 15;
    int deg = cnt[node];
    if (deg > SLOTS) deg = SLOTS;

    float4 self = g4[(size_t)node * 16 + sub];  // hoisted: overlaps loop latency
    float dvv = dinv_of(deg);

    int av = (lane < deg) ? adj[node * SLOTS + lane] : 0;  // one coalesced load

    float ax = 0.f, ay = 0.f, az = 0.f, aw = 0.f;
#pragma unroll 8
    for (int q = 0; q < 16; ++q) {
        int slot = 4 * q + grp;
        if (4 * q >= deg) break;        // wave-uniform exit
        int s = __shfl(av, slot);
        if (slot < deg) {               // uniform per 16-lane group
            float4 v = g4[(size_t)s * 16 + sub];
            ax += v.x; ay += v.y; az += v.z; aw += v.w;
        }
    }
#pragma unroll
    for (int m = 16; m <= 32; m <<= 1) {
        ax += __shfl_xor(ax, m);
        ay += __shfl_xor(ay, m);
        az += __shfl_xor(az, m);
        aw += __shfl_xor(aw, m);
    }
    if (lane < 16) {
        float4 r;
        r.x = (ax + self.x) * dvv;
        r.y = (ay + self.y) * dvv;
        r.z = (az + self.z) * dvv;
        r.w = (aw + self.w) * dvv;
        agg4[(size_t)node * 16 + sub] = r;
    }
}

// ---------- pool + fc ----------
__device__ __forceinline__ int lower_bound_batch(const int* __restrict__ batch, int n, int val) {
    int lo = 0, hi = n;
    while (lo < hi) {
        int mid = (lo + hi) >> 1;
        if (batch[mid] < val) lo = mid + 1; else hi = mid;
    }
    return lo;
}

__global__ void k_pool_part(const float* __restrict__ agg, const float* __restrict__ b3,
                            const int* __restrict__ batch, float* __restrict__ part, int n) {
    int b = blockIdx.x / PS;
    int s = blockIdx.x % PS;
    int lo = lower_bound_batch(batch, n, b);
    int hi = lower_bound_batch(batch, n, b + 1);
    int len = hi - lo;
    int c0 = lo + (int)((long long)len * s / PS);
    int c1 = lo + (int)((long long)len * (s + 1) / PS);

    int j = threadIdx.x & 63;
    int w = threadIdx.x >> 6;
    float bj = b3[j];
    float acc = 0.0f;
    for (int node = c0 + w; node < c1; node += 4)
        acc += fmaxf(agg[(size_t)node * DH + j] + bj, 0.0f);

    __shared__ float red[4][DH];
    red[w][j] = acc;
    __syncthreads();
    if (w == 0)
        part[(b * PS + s) * DH + j] = red[0][j] + red[1][j] + red[2][j] + red[3][j];
}

__global__ void k_fc(const float* __restrict__ part, const int* __restrict__ batch,
                     const float* __restrict__ Wfc, const float* __restrict__ bfc,
                     float* __restrict__ out, int n) {
    int b = blockIdx.x;
    int j = threadIdx.x;  // 64 threads = 1 wave
    int lo = lower_bound_batch(batch, n, b);
    int hi = lower_bound_batch(batch, n, b + 1);
    float c = fmaxf((float)(hi - lo), 1.0f);
    float p = 0.0f;
#pragma unroll
    for (int s = 0; s < PS; ++s) p += part[(b * PS + s) * DH + j];
    p = (p / c) * Wfc[j];
#pragma unroll
    for (int off = 32; off; off >>= 1) p += __shfl_down(p, off);
    if (j == 0) out[b] = p + bfc[0];
}

extern "C" void kernel_launch(void* const* d_in, const int* in_sizes, int n_in,
                              void* d_out, int out_size, void* d_ws, size_t ws_size,
                              hipStream_t stream) {
    const float* x    = (const float*)d_in[0];
    const int* ei     = (const int*)d_in[1];
    const int* batch  = (const int*)d_in[2];
    const float* W1   = (const float*)d_in[3];
    const float* b1   = (const float*)d_in[4];
    const float* W2   = (const float*)d_in[5];
    const float* b2   = (const float*)d_in[6];
    const float* W3   = (const float*)d_in[7];
    const float* b3   = (const float*)d_in[8];
    const float* Wfc  = (const float*)d_in[9];
    const float* bfc  = (const float*)d_in[10];
    float* out = (float*)d_out;

    const int n = in_sizes[0] / DI;  // 50000
    const int e = in_sizes[1] / 2;   // 800000 (divisible by 4; dst = ei+e stays 16B-aligned)
    const int* src = ei;
    const int* dst = ei + e;

    // workspace layout (ws_size = 256 MiB; all blocks 16B-aligned)
    float* h      = (float*)d_ws;               // n*DH
    float* agg    = h + (size_t)n * DH;         // n*DH
    float* part   = agg + (size_t)n * DH;       // NB*PS*DH
    int*   cursor = (int*)(part + NB * PS * DH);// n   (doubles as in-degree after fill)
    int*   adj    = cursor + n;                 // n*SLOTS

    const int e4    = e / 4;          // 200000 int4 edge groups
    const int fb    = (e4 + 255) / 256;
    const int wb4   = (n + 3) / 4;    // 1 wave per node kernels
    const int gmb   = (n + 63) / 64;  // gemm blocks (64 nodes each)
    const int chunk = (n + NXCD - 1) / NXCD;  // dst-partition size (6250)
    const int zw4   = n / 4;          // cursor int4 words (50000 % 4 == 0)

    // ---- adjacency build: one zero + one fused count/fill pass ----
    k_zero<<<(zw4 + 255) / 256, 256, 0, stream>>>((int4*)cursor, zw4);
    k_fill<<<fb * NXCD, 256, 0, stream>>>((const int4*)src, (const int4*)dst,
                                          cursor, adj, e4, chunk);

    // ---- layers ----
    k_matmul<DI, false><<<gmb, 256, 0, stream>>>((const float4*)x, (const float4*)W1,
                                                 nullptr, cursor, (float4*)h, n);
    k_gather<<<wb4, 256, 0, stream>>>(cursor, adj, (const float4*)h, (float4*)agg, n);
    k_matmul<DH, true><<<gmb, 256, 0, stream>>>((const float4*)agg, (const float4*)W2,
                                                (const float4*)b1, cursor, (float4*)h, n);
    k_gather<<<wb4, 256, 0, stream>>>(cursor, adj, (const float4*)h, (float4*)agg, n);
    k_matmul<DH, true><<<gmb, 256, 0, stream>>>((const float4*)agg, (const float4*)W3,
                                                (const float4*)b2, cursor, (float4*)h, n);
    k_gather<<<wb4, 256, 0, stream>>>(cursor, adj, (const float4*)h, (float4*)agg, n);

    // ---- pool + fc ----
    k_pool_part<<<NB * PS, 256, 0, stream>>>(agg, b3, batch, part, n);
    k_fc<<<NB, DH, 0, stream>>>(part, batch, Wfc, bfc, out, n);
}